// Round 18
// baseline (2282.206 us; speedup 1.0000x reference)
//
#include <hip/hip_runtime.h>
#include <math.h>

// ---------------------------------------------------------------------------
// skel_net. Numerics model v19 (bit-level evidence, rounds 0-20):
//   float32 numpy reference. Pinned by experiment:
//     - conv l1/l2/l3: c_einsum separate mul+add, c-ascending, acc 0,
//       bias AFTER, relu; l3 bias per col BEFORE max. [R9/R14/R20]
//     - fc1 K=1024 -> panels 512|512, FMA chains, C += panel. [R12 vs R18]
//     - fc2 K=512 -> single whole-K FMA chain. [R19 vs R18]
//     - fc3 K=256 -> panels 128|128. [R21]
//     - tail: f32 elementwise numpy op order.
//
// PERF LOG (this session):
//   R0/R2: packed weights -> coalesced loads. 5662 -> 4430 us.
//   R5: h2t transpose + l3 4x1row: VGPR 92, 3246 us.
//   R6: split k_conv/k_fc: k_conv VGPR=32, Occ 87%, issue-saturated. 2385.
//   R8: float2 "pk" (compiler scalarized): 2034 us (halved LDS reads).
//   R15: inline-asm v_pk: 1939 us (k_conv 1470). v_pk_*_f32 is
//       throughput-NEUTRAL (4-cyc issue); l3 MAC floor ~930us is hard
//       (FMA forbidden by pinned mul+add rounding).
//   R17: b128-merge + weight prefetch REGRESSED k_conv 1470->1535 (mov
//       overhead extracting asm pair operands; prefetch folded by RA).
//       REVERTED to R15 l3 body.
//   THIS ROUND:
//     (a) l3 = R15-exact (2x ds_read_b64 -> v2f, no prefetch).
//     (b) k_fc SPB 4 -> 8: every block streams fw1p(2MB)+fw2p(0.5MB) from
//         L2; 4096 blocks = ~10.7 GB ~ 320us at L2 BW == measured k_fc.
//         SPB=8 halves that. LDS ~59KB (2 blocks/CU). Per-sample FP
//         chains unchanged -> bit-exact.
//     (c) tail scratch strides 264/72 kept (2-way conflict = free).
// ---------------------------------------------------------------------------

#define BATCH 16384
#define SPB 8  // samples per block in k_fc

typedef float v2f __attribute__((ext_vector_type(2)));

__device__ __constant__ int c_parents[19] = {-1, 0, 1, 2, 3, 0, 5, 6, 7, 0,
                                             9, 10, 11, 8, 13, 14, 8, 16, 17};

// Packed weights.
// g_w2p: [k4][o][4] for l2 (row-per-lane coalesced float4).
// g_w3q: [h][k4][rw] float4 = {w3[rw][4k4+2h], w3[rw+512][4k4+2h],
//                              w3[rw][4k4+2h+1], w3[rw+512][4k4+2h+1]}
//        -> one float4 = two adjacent v2f pairs for row pair (rw, rw+512).
__device__ float4 g_w2p[16 * 128];    //  8192 floats
__device__ float4 g_w3q[2 * 32 * 512];  // 131072 floats
__device__ float4 g_fw1p[256 * 512];  // 524288 floats
__device__ float4 g_fw2p[128 * 256];  // 131072 floats
__device__ float4 g_fw3p[64 * 79];    //  20224 floats

// pooled features staging (k_conv -> k_fc), 67 MB
__device__ float g_feat[BATCH * 1024];

// total packed floats = 8192+131072+524288+131072+20224 = 814848
#define PACK_TOTAL 814848

__global__ __launch_bounds__(256) void k_pack(
    const float* __restrict__ w2, const float* __restrict__ w3,
    const float* __restrict__ fw1, const float* __restrict__ fw2,
    const float* __restrict__ fw3) {
  int i = blockIdx.x * 256 + threadIdx.x;
  // w2p [k4][128][4], k4<16
  if (i < 8192) {
    int c = i & 3, o = (i >> 2) & 127, k4 = i >> 9;
    ((float*)g_w2p)[i] = w2[o * 64 + k4 * 4 + c];
    return;
  }
  i -= 8192;
  // w3q: float4 index f = (h*32 + k4)*512 + rw; elem c:
  //   row = rw + (c&1)*512, comp k = k4*4 + 2*h + (c>>1)
  if (i < 131072) {
    int c = i & 3;
    int f = i >> 2;
    int rw = f & 511;
    int k4 = (f >> 9) & 31;
    int h = f >> 14;
    int row = rw + (c & 1) * 512;
    int kk = k4 * 4 + 2 * h + (c >> 1);
    ((float*)g_w3q)[i] = w3[row * 128 + kk];
    return;
  }
  i -= 131072;
  // fw1p [k4][512][4], k4<256
  if (i < 524288) {
    int c = i & 3, o = (i >> 2) & 511, k4 = i >> 11;
    ((float*)g_fw1p)[i] = fw1[o * 1024 + k4 * 4 + c];
    return;
  }
  i -= 524288;
  // fw2p [k4][256][4], k4<128
  if (i < 131072) {
    int c = i & 3, o = (i >> 2) & 255, k4 = i >> 10;
    ((float*)g_fw2p)[i] = fw2[o * 512 + k4 * 4 + c];
    return;
  }
  i -= 131072;
  // fw3p [k4][79][4], k4<64
  if (i < 20224) {
    int c = i & 3;
    int o = (i >> 2) % 79;
    int k4 = (i >> 2) / 79;
    ((float*)g_fw3p)[i] = fw3[o * 256 + k4 * 4 + c];
  }
}

// ======================= kernel A: conv stack, 1 sample/block =============
__global__ __launch_bounds__(256) void k_conv(
    const float* __restrict__ x,
    const float* __restrict__ w1, const float* __restrict__ b1,
    const float* __restrict__ b2, const float* __restrict__ b3) {
#pragma clang fp contract(off)
  __shared__ float sh_scr[3264];  // h1[1088] + h2t[17][128]
  __shared__ float sh_x[34];

  const int t = threadIdx.x;
  const int sample = blockIdx.x;

  if (t < 34) sh_x[t] = x[sample * 34 + t];
  __syncthreads();

  // ---- l1: out[o,p] = relu((w1[o,0]*x0p + w1[o,1]*x1p) + b1[o])
  for (int idx = t; idx < 1088; idx += 256) {
    int o = idx / 17, p = idx - o * 17;
    float v = w1[2 * o] * sh_x[p];        // c=0: 0 + w*x
    v = v + w1[2 * o + 1] * sh_x[17 + p]; // c=1
    v = v + b1[o];                        // bias AFTER contraction
    sh_scr[idx] = v > 0.0f ? v : 0.0f;    // h1 at scr[0..1088)
  }
  __syncthreads();

  // ---- l2: 128 outputs x 17 cols, K=64. plain mul+add, c ascending.
  //      OUTPUT STORED TRANSPOSED: h2t[p][o] at scr[1088 + p*128 + o].
  {
    int o = t & 127;
    int half = t >> 7;  // wave-uniform
    int pb = half * 9;
    int ncol = half ? 8 : 9;
    float acc[9];
#pragma unroll
    for (int j = 0; j < 9; ++j) acc[j] = 0.0f;
    for (int k4 = 0; k4 < 16; ++k4) {
      float4 f = g_w2p[k4 * 128 + o];   // coalesced packed load
      const float* hr = &sh_scr[(k4 * 4) * 17 + pb];
#pragma unroll
      for (int j = 0; j < 9; ++j)
        if (j < ncol) {
          float a = acc[j];
          a = a + f.x * hr[j];
          a = a + f.y * hr[17 + j];
          a = a + f.z * hr[34 + j];
          a = a + f.w * hr[51 + j];
          acc[j] = a;
        }
    }
    float bb = b2[o];
#pragma unroll
    for (int j = 0; j < 9; ++j)
      if (j < ncol) {
        float v = acc[j] + bb;  // bias after
        sh_scr[1088 + (pb + j) * 128 + o] = v > 0.0f ? v : 0.0f;
      }
  }
  __syncthreads();

  // ---- l3 + max: 1024 rows x 17 cols, K=128. R15-exact: inline-asm
  //      packed fp32 on row pair (rw, rw+512); 2x ds_read_b64 -> v2f.
  //      Per-element chain identical to scalar (c ascending, mul then
  //      add, bias after, relu-floor max over p) -> bit-exact.
  const float* h2p = &sh_scr[1088];
  const v2f* wv = (const v2f*)g_w3q;
  for (int rg = 0; rg < 2; ++rg) {
    int rw = t + rg * 256;  // rows rw and rw+512
    v2f a[17];
#pragma unroll
    for (int p = 0; p < 17; ++p) a[p] = (v2f){0.0f, 0.0f};
    for (int k4 = 0; k4 < 32; ++k4) {
      int i0 = (k4 * 512 + rw) * 2;          // q0 -> pairs f0 (c=x), f1 (c=y)
      int i1 = (16384 + k4 * 512 + rw) * 2;  // q1 -> pairs f2 (c=z), f3 (c=w)
      v2f f0 = wv[i0];
      v2f f1 = wv[i0 + 1];
      v2f f2 = wv[i1];
      v2f f3 = wv[i1 + 1];
#pragma unroll
      for (int p = 0; p < 17; ++p) {
        // broadcast ds_read (wave-uniform addr): h2t[p][k4*4 .. +3]
        v2f hxy = *(const v2f*)&h2p[p * 128 + k4 * 4];
        v2f hzw = *(const v2f*)&h2p[p * 128 + k4 * 4 + 2];
        v2f t0, t1, t2, t3;
        // c=0: a += f0 * bcast(hxy.lo)
        asm("v_pk_mul_f32 %0, %1, %2 op_sel:[0,0] op_sel_hi:[1,0]"
            : "=v"(t0) : "v"(f0), "v"(hxy));
        asm("v_pk_add_f32 %0, %0, %1" : "+v"(a[p]) : "v"(t0));
        // c=1: a += f1 * bcast(hxy.hi)
        asm("v_pk_mul_f32 %0, %1, %2 op_sel:[0,1] op_sel_hi:[1,1]"
            : "=v"(t1) : "v"(f1), "v"(hxy));
        asm("v_pk_add_f32 %0, %0, %1" : "+v"(a[p]) : "v"(t1));
        // c=2: a += f2 * bcast(hzw.lo)
        asm("v_pk_mul_f32 %0, %1, %2 op_sel:[0,0] op_sel_hi:[1,0]"
            : "=v"(t2) : "v"(f2), "v"(hzw));
        asm("v_pk_add_f32 %0, %0, %1" : "+v"(a[p]) : "v"(t2));
        // c=3: a += f3 * bcast(hzw.hi)
        asm("v_pk_mul_f32 %0, %1, %2 op_sel:[0,1] op_sel_hi:[1,1]"
            : "=v"(t3) : "v"(f3), "v"(hzw));
        asm("v_pk_add_f32 %0, %0, %1" : "+v"(a[p]) : "v"(t3));
      }
    }
    float bb0 = b3[rw], bb1 = b3[rw + 512];
    float m0 = 0.0f, m1 = 0.0f;  // relu floor
#pragma unroll
    for (int p = 0; p < 17; ++p) {
      float v0 = a[p][0] + bb0;  // bias per column, rounds, THEN max
      float v1 = a[p][1] + bb1;
      m0 = fmaxf(m0, v0);
      m1 = fmaxf(m1, v1);
    }
    g_feat[sample * 1024 + rw] = m0;
    g_feat[sample * 1024 + rw + 512] = m1;
  }
}

// ======================= kernel B: fc stack + tail, SPB samples/block =====
__global__ __launch_bounds__(256) void k_fc(
    const float* __restrict__ fb1,
    const float* __restrict__ fb2,
    const float* __restrict__ fb3,
    float* __restrict__ out) {
#pragma clang fp contract(off)
  __shared__ float sh_g[SPB * 1024];   // staged pooled features; later FK scratch
  __shared__ float sh_scr[SPB * 768];  // g1[SPB*512] + g2[SPB*256]
  __shared__ float sh_q[SPB * 79];     // out_q per block

  const int t = threadIdx.x;

  // stage g (coalesced float4)
  {
    const float4* src = (const float4*)(g_feat + blockIdx.x * (SPB * 1024));
    float4* dst = (float4*)sh_g;
    for (int i = t; i < SPB * 256; i += 256) dst[i] = src[i];
  }
  __syncthreads();

  // ============ fc1: 512 outputs, K=1024 = panels 512|512, FMA ============
  {
    int o0 = t, o1 = t + 256;
    float tot0[SPB], tot1[SPB];
    const int blk[3] = {0, 128, 256};  // float4 units: 512|512
#pragma unroll
    for (int s = 0; s < SPB; ++s) { tot0[s] = 0.0f; tot1[s] = 0.0f; }
    for (int b = 0; b < 2; ++b) {
      float s0[SPB], s1[SPB];
#pragma unroll
      for (int s = 0; s < SPB; ++s) { s0[s] = 0.0f; s1[s] = 0.0f; }
      for (int k4 = blk[b]; k4 < blk[b + 1]; ++k4) {
        float4 f0 = g_fw1p[k4 * 512 + o0];  // coalesced packed loads
        float4 f1 = g_fw1p[k4 * 512 + o1];
#pragma unroll
        for (int s = 0; s < SPB; ++s) {
          const float* gp = &sh_g[s * 1024 + k4 * 4];
          float g0 = gp[0], g1v = gp[1], g2v = gp[2], g3v = gp[3];
          s0[s] = fmaf(f0.w, g3v, fmaf(f0.z, g2v, fmaf(f0.y, g1v, fmaf(f0.x, g0, s0[s]))));
          s1[s] = fmaf(f1.w, g3v, fmaf(f1.z, g2v, fmaf(f1.y, g1v, fmaf(f1.x, g0, s1[s]))));
        }
      }
#pragma unroll
      for (int s = 0; s < SPB; ++s) {  // C += panel partial (one rounding)
        tot0[s] = tot0[s] + s0[s];
        tot1[s] = tot1[s] + s1[s];
      }
    }
    __syncthreads();
    float bb0 = fb1[o0], bb1 = fb1[o1];
#pragma unroll
    for (int s = 0; s < SPB; ++s) {
      float v0 = tot0[s] + bb0;
      float v1 = tot1[s] + bb1;
      sh_scr[s * 512 + o0] = v0 > 0.0f ? v0 : 0.0f;  // g1 at scr[0..SPB*512)
      sh_scr[s * 512 + o1] = v1 > 0.0f ? v1 : 0.0f;
    }
  }
  __syncthreads();

  // ============ fc2: 256 outputs, K=512 = single whole-K chain, FMA =======
  {
    int o = t;
    float tot[SPB];
#pragma unroll
    for (int s = 0; s < SPB; ++s) tot[s] = 0.0f;
    for (int k4 = 0; k4 < 128; ++k4) {
      float4 f = g_fw2p[k4 * 256 + o];  // coalesced packed load
#pragma unroll
      for (int s = 0; s < SPB; ++s) {
        const float* gp = &sh_scr[s * 512 + k4 * 4];
        tot[s] = fmaf(f.w, gp[3], fmaf(f.z, gp[2], fmaf(f.y, gp[1], fmaf(f.x, gp[0], tot[s]))));
      }
    }
    float bb = fb2[o];
#pragma unroll
    for (int s = 0; s < SPB; ++s) {
      float v = tot[s] + bb;
      sh_scr[SPB * 512 + s * 256 + o] = v > 0.0f ? v : 0.0f;  // g2
    }
  }
  __syncthreads();

  // ============ fc3: 79 outputs, K=256 = panels 128|128, FMA ==============
  for (int idx = t; idx < SPB * 79; idx += 256) {
    int s = idx / 79, o = idx - s * 79;
    float tot = 0.0f;
    for (int b = 0; b < 2; ++b) {
      float a = 0.0f;
      for (int k4 = b * 32; k4 < (b + 1) * 32; ++k4) {
        float4 f = g_fw3p[k4 * 79 + o];  // coalesced packed load
        const float* gp = &sh_scr[SPB * 512 + s * 256 + k4 * 4];
        a = fmaf(f.w, gp[3], fmaf(f.z, gp[2], fmaf(f.y, gp[1], fmaf(f.x, gp[0], a))));
      }
      tot = tot + a;  // combine partials: (0 + p0) + p1
    }
    sh_q[s * 79 + o] = tot + fb3[o];
  }
  __syncthreads();

  // ============ tail: quat->rot, FK, projection -- f32 numpy op order =====
  // Scratch strides de-conflicted: R stride 264, P stride 72 -> lanes hit
  // banks {0,8,16,24} pattern (2-way for SPB=8, which is free).
  if (t < SPB) {
    const int s = t;
    const int sample = blockIdx.x * SPB + s;
    float* R = &sh_g[s * 264];               // 171 floats (sh_g dead)
    float* P = &sh_g[SPB * 264 + s * 72];    // 57 floats
    const float* qf = &sh_q[s * 79];

    for (int j = 0; j < 19; ++j) {
      float w = qf[3 + 4 * j], xx = qf[4 + 4 * j];
      float yy = qf[5 + 4 * j], zz = qf[6 + 4 * j];
      float n = sqrtf(((w * w + xx * xx) + yy * yy) + zz * zz) + 1e-8f;
      w = w / n; xx = xx / n; yy = yy / n; zz = zz / n;
      R[j * 9 + 0] = 1.0f - 2.0f * (yy * yy + zz * zz);
      R[j * 9 + 1] = 2.0f * (xx * yy - w * zz);
      R[j * 9 + 2] = 2.0f * (xx * zz + w * yy);
      R[j * 9 + 3] = 2.0f * (xx * yy + w * zz);
      R[j * 9 + 4] = 1.0f - 2.0f * (xx * xx + zz * zz);
      R[j * 9 + 5] = 2.0f * (yy * zz - w * xx);
      R[j * 9 + 6] = 2.0f * (xx * zz - w * yy);
      R[j * 9 + 7] = 2.0f * (yy * zz + w * xx);
      R[j * 9 + 8] = 1.0f - 2.0f * (xx * xx + yy * yy);
    }
    P[0] = qf[0]; P[1] = qf[1]; P[2] = qf[2];

    // OFFSETS = np.linspace(0.2,0.6,18) f64 -> astype(f32); y[17]=0.6
    const double step = (0.6 - 0.2) / 17.0;
    for (int j = 1; j < 19; ++j) {
      int p = c_parents[j];
      double ov = (double)(j - 1) * step + 0.2;
      if (j == 18) ov = 0.6;
      float offy = (float)ov;
      // 'bij,j->bi' over offs=(0,offy,0): zero products exact either order
      float t0 = R[p * 9 + 1] * offy;
      float t1 = R[p * 9 + 4] * offy;
      float t2 = R[p * 9 + 7] * offy;
      P[j * 3 + 0] = P[p * 3 + 0] + t0;
      P[j * 3 + 1] = P[p * 3 + 1] + t1;
      P[j * 3 + 2] = P[p * 3 + 2] + t2;
      // rotg[j] = rotg[p] @ R[j]: c_einsum scalar, (p0+p1)+p2
      float m[9];
#pragma unroll
      for (int i = 0; i < 3; ++i)
#pragma unroll
        for (int c = 0; c < 3; ++c) {
          float p0 = R[p * 9 + i * 3 + 0] * R[j * 9 + 0 + c];
          float p1 = R[p * 9 + i * 3 + 1] * R[j * 9 + 3 + c];
          float p2 = R[p * 9 + i * 3 + 2] * R[j * 9 + 6 + c];
          m[i * 3 + c] = (p0 + p1) + p2;
        }
#pragma unroll
      for (int e = 0; e < 9; ++e) R[j * 9 + e] = m[e];
    }

    // output 1: P / (1.0f + 1e-9f) == P exactly in f32
    float* outPos = out + BATCH * 34 + sample * 57;
    for (int j = 0; j < 19; ++j) {
      outPos[j * 3 + 0] = P[j * 3 + 0];
      outPos[j * 3 + 1] = P[j * 3 + 1];
      outPos[j * 3 + 2] = P[j * 3 + 2];
    }

    // output 0: pose2d joints 0..8,11..18: x/(z+eps), (y-100)/(z+eps)
    float* out2d = out + sample * 34;
    int jj = 0;
    for (int j = 0; j < 19; ++j) {
      if (j == 9 || j == 10) continue;
      float zd = P[j * 3 + 2] + 1e-9f;
      float ym = P[j * 3 + 1] - 100.0f;
      out2d[jj * 2 + 0] = P[j * 3 + 0] / zd;
      out2d[jj * 2 + 1] = ym / zd;
      ++jj;
    }
  }
}

// ---------------------------------------------------------------------------
extern "C" void kernel_launch(void* const* d_in, const int* in_sizes, int n_in,
                              void* d_out, int out_size, void* d_ws, size_t ws_size,
                              hipStream_t stream) {
  const float* x   = (const float*)d_in[0];
  const float* w1  = (const float*)d_in[1];
  const float* b1  = (const float*)d_in[2];
  const float* w2  = (const float*)d_in[3];
  const float* b2  = (const float*)d_in[4];
  const float* w3  = (const float*)d_in[5];
  const float* b3  = (const float*)d_in[6];
  const float* fw1 = (const float*)d_in[7];
  const float* fb1 = (const float*)d_in[8];
  const float* fw2 = (const float*)d_in[9];
  const float* fb2 = (const float*)d_in[10];
  const float* fw3 = (const float*)d_in[11];
  const float* fb3 = (const float*)d_in[12];
  float* out = (float*)d_out;

  // pack weights for coalesced / pk-pair access (bit-exact: pure relocation)
  hipLaunchKernelGGL(k_pack, dim3((PACK_TOTAL + 255) / 256), dim3(256), 0, stream,
                     w2, w3, fw1, fw2, fw3);

  // conv stack: 1 sample per block
  hipLaunchKernelGGL(k_conv, dim3(BATCH), dim3(256), 0, stream,
                     x, w1, b1, b2, b3);

  // fc stack + tail: SPB samples per block
  hipLaunchKernelGGL(k_fc, dim3(BATCH / SPB), dim3(256), 0, stream,
                     fb1, fb2, fb3, out);
}

// Round 19
// 1843.242 us; speedup vs baseline: 1.2381x; 1.2381x over previous
//
#include <hip/hip_runtime.h>
#include <math.h>

// ---------------------------------------------------------------------------
// skel_net. Numerics model v19 (bit-level evidence, rounds 0-20):
//   float32 numpy reference. Pinned by experiment:
//     - conv l1/l2/l3: c_einsum separate mul+add, c-ascending, acc 0,
//       bias AFTER, relu; l3 bias per col BEFORE max. [R9/R14/R20]
//     - fc1 K=1024 -> panels 512|512, FMA chains, C += panel. [R12 vs R18]
//     - fc2 K=512 -> single whole-K FMA chain. [R19 vs R18]
//     - fc3 K=256 -> panels 128|128. [R21]
//     - tail: f32 elementwise numpy op order.
//
// PERF LOG (this session):
//   R0/R2: packed weights -> coalesced loads. 5662 -> 4430 us.
//   R5: h2t transpose + l3 4x1row: VGPR 92, 3246 us.
//   R6: split k_conv/k_fc: k_conv VGPR=32, Occ 87%, issue-saturated. 2385.
//   R8: float2 "pk" (compiler scalarized): 2034 us (halved LDS reads).
//   R15: inline-asm v_pk: 1939 us (k_conv 1470). v_pk_*_f32 is
//       throughput-NEUTRAL on the data path (fp32 mul/add = 78.6 TF;
//       157.3 TF spec is FMA); gain was issue-slot reduction. l3 MAC
//       floor ~930us is hard (FMA forbidden by pinned rounding).
//   R17: b128-merge + weight prefetch REGRESSED (mov overhead). REVERTED.
//   R18: k_fc SPB=8 REGRESSED (k_fc 440->790: VGPR/LDS occupancy cost >
//       L2 traffic saved). REVERTED to SPB=4.
//   THIS ROUND: best-known config = R15-exact l3 + SPB=4 k_fc + cost-free
//       tail de-conflict (R stride 264 / P stride 72 -> banks {0,8,16,24},
//       attacks SQ_LDS_BANK_CONFLICT=1.29e7). Expect ~1900-1945 us; this
//       is ~70% of the bit-exactness-constrained mul+add issue roofline.
// ---------------------------------------------------------------------------

#define BATCH 16384
#define SPB 4  // samples per block in k_fc

typedef float v2f __attribute__((ext_vector_type(2)));

__device__ __constant__ int c_parents[19] = {-1, 0, 1, 2, 3, 0, 5, 6, 7, 0,
                                             9, 10, 11, 8, 13, 14, 8, 16, 17};

// Packed weights.
// g_w2p: [k4][o][4] for l2 (row-per-lane coalesced float4).
// g_w3q: [h][k4][rw] float4 = {w3[rw][4k4+2h], w3[rw+512][4k4+2h],
//                              w3[rw][4k4+2h+1], w3[rw+512][4k4+2h+1]}
//        -> one float4 = two adjacent v2f pairs for row pair (rw, rw+512).
__device__ float4 g_w2p[16 * 128];    //  8192 floats
__device__ float4 g_w3q[2 * 32 * 512];  // 131072 floats
__device__ float4 g_fw1p[256 * 512];  // 524288 floats
__device__ float4 g_fw2p[128 * 256];  // 131072 floats
__device__ float4 g_fw3p[64 * 79];    //  20224 floats

// pooled features staging (k_conv -> k_fc), 67 MB
__device__ float g_feat[BATCH * 1024];

// total packed floats = 8192+131072+524288+131072+20224 = 814848
#define PACK_TOTAL 814848

__global__ __launch_bounds__(256) void k_pack(
    const float* __restrict__ w2, const float* __restrict__ w3,
    const float* __restrict__ fw1, const float* __restrict__ fw2,
    const float* __restrict__ fw3) {
  int i = blockIdx.x * 256 + threadIdx.x;
  // w2p [k4][128][4], k4<16
  if (i < 8192) {
    int c = i & 3, o = (i >> 2) & 127, k4 = i >> 9;
    ((float*)g_w2p)[i] = w2[o * 64 + k4 * 4 + c];
    return;
  }
  i -= 8192;
  // w3q: float4 index f = (h*32 + k4)*512 + rw; elem c:
  //   row = rw + (c&1)*512, comp k = k4*4 + 2*h + (c>>1)
  if (i < 131072) {
    int c = i & 3;
    int f = i >> 2;
    int rw = f & 511;
    int k4 = (f >> 9) & 31;
    int h = f >> 14;
    int row = rw + (c & 1) * 512;
    int kk = k4 * 4 + 2 * h + (c >> 1);
    ((float*)g_w3q)[i] = w3[row * 128 + kk];
    return;
  }
  i -= 131072;
  // fw1p [k4][512][4], k4<256
  if (i < 524288) {
    int c = i & 3, o = (i >> 2) & 511, k4 = i >> 11;
    ((float*)g_fw1p)[i] = fw1[o * 1024 + k4 * 4 + c];
    return;
  }
  i -= 524288;
  // fw2p [k4][256][4], k4<128
  if (i < 131072) {
    int c = i & 3, o = (i >> 2) & 255, k4 = i >> 10;
    ((float*)g_fw2p)[i] = fw2[o * 512 + k4 * 4 + c];
    return;
  }
  i -= 131072;
  // fw3p [k4][79][4], k4<64
  if (i < 20224) {
    int c = i & 3;
    int o = (i >> 2) % 79;
    int k4 = (i >> 2) / 79;
    ((float*)g_fw3p)[i] = fw3[o * 256 + k4 * 4 + c];
  }
}

// ======================= kernel A: conv stack, 1 sample/block =============
__global__ __launch_bounds__(256) void k_conv(
    const float* __restrict__ x,
    const float* __restrict__ w1, const float* __restrict__ b1,
    const float* __restrict__ b2, const float* __restrict__ b3) {
#pragma clang fp contract(off)
  __shared__ float sh_scr[3264];  // h1[1088] + h2t[17][128]
  __shared__ float sh_x[34];

  const int t = threadIdx.x;
  const int sample = blockIdx.x;

  if (t < 34) sh_x[t] = x[sample * 34 + t];
  __syncthreads();

  // ---- l1: out[o,p] = relu((w1[o,0]*x0p + w1[o,1]*x1p) + b1[o])
  for (int idx = t; idx < 1088; idx += 256) {
    int o = idx / 17, p = idx - o * 17;
    float v = w1[2 * o] * sh_x[p];        // c=0: 0 + w*x
    v = v + w1[2 * o + 1] * sh_x[17 + p]; // c=1
    v = v + b1[o];                        // bias AFTER contraction
    sh_scr[idx] = v > 0.0f ? v : 0.0f;    // h1 at scr[0..1088)
  }
  __syncthreads();

  // ---- l2: 128 outputs x 17 cols, K=64. plain mul+add, c ascending.
  //      OUTPUT STORED TRANSPOSED: h2t[p][o] at scr[1088 + p*128 + o].
  {
    int o = t & 127;
    int half = t >> 7;  // wave-uniform
    int pb = half * 9;
    int ncol = half ? 8 : 9;
    float acc[9];
#pragma unroll
    for (int j = 0; j < 9; ++j) acc[j] = 0.0f;
    for (int k4 = 0; k4 < 16; ++k4) {
      float4 f = g_w2p[k4 * 128 + o];   // coalesced packed load
      const float* hr = &sh_scr[(k4 * 4) * 17 + pb];
#pragma unroll
      for (int j = 0; j < 9; ++j)
        if (j < ncol) {
          float a = acc[j];
          a = a + f.x * hr[j];
          a = a + f.y * hr[17 + j];
          a = a + f.z * hr[34 + j];
          a = a + f.w * hr[51 + j];
          acc[j] = a;
        }
    }
    float bb = b2[o];
#pragma unroll
    for (int j = 0; j < 9; ++j)
      if (j < ncol) {
        float v = acc[j] + bb;  // bias after
        sh_scr[1088 + (pb + j) * 128 + o] = v > 0.0f ? v : 0.0f;
      }
  }
  __syncthreads();

  // ---- l3 + max: 1024 rows x 17 cols, K=128. R15-exact: inline-asm
  //      packed fp32 on row pair (rw, rw+512); 2x ds_read_b64 -> v2f.
  //      Per-element chain identical to scalar (c ascending, mul then
  //      add, bias after, relu-floor max over p) -> bit-exact.
  const float* h2p = &sh_scr[1088];
  const v2f* wv = (const v2f*)g_w3q;
  for (int rg = 0; rg < 2; ++rg) {
    int rw = t + rg * 256;  // rows rw and rw+512
    v2f a[17];
#pragma unroll
    for (int p = 0; p < 17; ++p) a[p] = (v2f){0.0f, 0.0f};
    for (int k4 = 0; k4 < 32; ++k4) {
      int i0 = (k4 * 512 + rw) * 2;          // q0 -> pairs f0 (c=x), f1 (c=y)
      int i1 = (16384 + k4 * 512 + rw) * 2;  // q1 -> pairs f2 (c=z), f3 (c=w)
      v2f f0 = wv[i0];
      v2f f1 = wv[i0 + 1];
      v2f f2 = wv[i1];
      v2f f3 = wv[i1 + 1];
#pragma unroll
      for (int p = 0; p < 17; ++p) {
        // broadcast ds_read (wave-uniform addr): h2t[p][k4*4 .. +3]
        v2f hxy = *(const v2f*)&h2p[p * 128 + k4 * 4];
        v2f hzw = *(const v2f*)&h2p[p * 128 + k4 * 4 + 2];
        v2f t0, t1, t2, t3;
        // c=0: a += f0 * bcast(hxy.lo)
        asm("v_pk_mul_f32 %0, %1, %2 op_sel:[0,0] op_sel_hi:[1,0]"
            : "=v"(t0) : "v"(f0), "v"(hxy));
        asm("v_pk_add_f32 %0, %0, %1" : "+v"(a[p]) : "v"(t0));
        // c=1: a += f1 * bcast(hxy.hi)
        asm("v_pk_mul_f32 %0, %1, %2 op_sel:[0,1] op_sel_hi:[1,1]"
            : "=v"(t1) : "v"(f1), "v"(hxy));
        asm("v_pk_add_f32 %0, %0, %1" : "+v"(a[p]) : "v"(t1));
        // c=2: a += f2 * bcast(hzw.lo)
        asm("v_pk_mul_f32 %0, %1, %2 op_sel:[0,0] op_sel_hi:[1,0]"
            : "=v"(t2) : "v"(f2), "v"(hzw));
        asm("v_pk_add_f32 %0, %0, %1" : "+v"(a[p]) : "v"(t2));
        // c=3: a += f3 * bcast(hzw.hi)
        asm("v_pk_mul_f32 %0, %1, %2 op_sel:[0,1] op_sel_hi:[1,1]"
            : "=v"(t3) : "v"(f3), "v"(hzw));
        asm("v_pk_add_f32 %0, %0, %1" : "+v"(a[p]) : "v"(t3));
      }
    }
    float bb0 = b3[rw], bb1 = b3[rw + 512];
    float m0 = 0.0f, m1 = 0.0f;  // relu floor
#pragma unroll
    for (int p = 0; p < 17; ++p) {
      float v0 = a[p][0] + bb0;  // bias per column, rounds, THEN max
      float v1 = a[p][1] + bb1;
      m0 = fmaxf(m0, v0);
      m1 = fmaxf(m1, v1);
    }
    g_feat[sample * 1024 + rw] = m0;
    g_feat[sample * 1024 + rw + 512] = m1;
  }
}

// ======================= kernel B: fc stack + tail, SPB samples/block =====
__global__ __launch_bounds__(256) void k_fc(
    const float* __restrict__ fb1,
    const float* __restrict__ fb2,
    const float* __restrict__ fb3,
    float* __restrict__ out) {
#pragma clang fp contract(off)
  __shared__ float sh_g[SPB * 1024];  // staged pooled features; later FK scratch
  __shared__ float sh_scr[3264];      // g1[2048]+g2[1024]
  __shared__ float sh_q[SPB * 79];    // out_q per block

  const int t = threadIdx.x;

  // stage g (coalesced float4)
  {
    const float4* src = (const float4*)(g_feat + blockIdx.x * (SPB * 1024));
    float4* dst = (float4*)sh_g;
    for (int i = t; i < SPB * 256; i += 256) dst[i] = src[i];
  }
  __syncthreads();

  // ============ fc1: 512 outputs, K=1024 = panels 512|512, FMA ============
  {
    int o0 = t, o1 = t + 256;
    float tot0[SPB], tot1[SPB];
    const int blk[3] = {0, 128, 256};  // float4 units: 512|512
#pragma unroll
    for (int s = 0; s < SPB; ++s) { tot0[s] = 0.0f; tot1[s] = 0.0f; }
    for (int b = 0; b < 2; ++b) {
      float s0[SPB], s1[SPB];
#pragma unroll
      for (int s = 0; s < SPB; ++s) { s0[s] = 0.0f; s1[s] = 0.0f; }
      for (int k4 = blk[b]; k4 < blk[b + 1]; ++k4) {
        float4 f0 = g_fw1p[k4 * 512 + o0];  // coalesced packed loads
        float4 f1 = g_fw1p[k4 * 512 + o1];
#pragma unroll
        for (int s = 0; s < SPB; ++s) {
          const float* gp = &sh_g[s * 1024 + k4 * 4];
          float g0 = gp[0], g1v = gp[1], g2v = gp[2], g3v = gp[3];
          s0[s] = fmaf(f0.w, g3v, fmaf(f0.z, g2v, fmaf(f0.y, g1v, fmaf(f0.x, g0, s0[s]))));
          s1[s] = fmaf(f1.w, g3v, fmaf(f1.z, g2v, fmaf(f1.y, g1v, fmaf(f1.x, g0, s1[s]))));
        }
      }
#pragma unroll
      for (int s = 0; s < SPB; ++s) {  // C += panel partial (one rounding)
        tot0[s] = tot0[s] + s0[s];
        tot1[s] = tot1[s] + s1[s];
      }
    }
    __syncthreads();
    float bb0 = fb1[o0], bb1 = fb1[o1];
#pragma unroll
    for (int s = 0; s < SPB; ++s) {
      float v0 = tot0[s] + bb0;
      float v1 = tot1[s] + bb1;
      sh_scr[s * 512 + o0] = v0 > 0.0f ? v0 : 0.0f;  // g1 at scr[0..2048)
      sh_scr[s * 512 + o1] = v1 > 0.0f ? v1 : 0.0f;
    }
  }
  __syncthreads();

  // ============ fc2: 256 outputs, K=512 = single whole-K chain, FMA =======
  {
    int o = t;
    float tot[SPB];
#pragma unroll
    for (int s = 0; s < SPB; ++s) tot[s] = 0.0f;
    for (int k4 = 0; k4 < 128; ++k4) {
      float4 f = g_fw2p[k4 * 256 + o];  // coalesced packed load
#pragma unroll
      for (int s = 0; s < SPB; ++s) {
        const float* gp = &sh_scr[s * 512 + k4 * 4];
        tot[s] = fmaf(f.w, gp[3], fmaf(f.z, gp[2], fmaf(f.y, gp[1], fmaf(f.x, gp[0], tot[s]))));
      }
    }
    float bb = fb2[o];
#pragma unroll
    for (int s = 0; s < SPB; ++s) {
      float v = tot[s] + bb;
      sh_scr[2048 + s * 256 + o] = v > 0.0f ? v : 0.0f;  // g2
    }
  }
  __syncthreads();

  // ============ fc3: 79 outputs, K=256 = panels 128|128, FMA ==============
  for (int idx = t; idx < SPB * 79; idx += 256) {
    int s = idx / 79, o = idx - s * 79;
    float tot = 0.0f;
    for (int b = 0; b < 2; ++b) {
      float a = 0.0f;
      for (int k4 = b * 32; k4 < (b + 1) * 32; ++k4) {
        float4 f = g_fw3p[k4 * 79 + o];  // coalesced packed load
        const float* gp = &sh_scr[2048 + s * 256 + k4 * 4];
        a = fmaf(f.w, gp[3], fmaf(f.z, gp[2], fmaf(f.y, gp[1], fmaf(f.x, gp[0], a))));
      }
      tot = tot + a;  // combine partials: (0 + p0) + p1
    }
    sh_q[s * 79 + o] = tot + fb3[o];
  }
  __syncthreads();

  // ============ tail: quat->rot, FK, projection -- f32 numpy op order =====
  // Scratch strides de-conflicted: R stride 264, P stride 72 -> the 4
  // active lanes hit banks {0,8,16,24} instead of all bank 0.
  if (t < SPB) {
    const int s = t;
    const int sample = blockIdx.x * SPB + s;
    float* R = &sh_g[s * 264];               // 171 floats (sh_g dead)
    float* P = &sh_g[2048 + s * 72];         // 57 floats
    const float* qf = &sh_q[s * 79];

    for (int j = 0; j < 19; ++j) {
      float w = qf[3 + 4 * j], xx = qf[4 + 4 * j];
      float yy = qf[5 + 4 * j], zz = qf[6 + 4 * j];
      float n = sqrtf(((w * w + xx * xx) + yy * yy) + zz * zz) + 1e-8f;
      w = w / n; xx = xx / n; yy = yy / n; zz = zz / n;
      R[j * 9 + 0] = 1.0f - 2.0f * (yy * yy + zz * zz);
      R[j * 9 + 1] = 2.0f * (xx * yy - w * zz);
      R[j * 9 + 2] = 2.0f * (xx * zz + w * yy);
      R[j * 9 + 3] = 2.0f * (xx * yy + w * zz);
      R[j * 9 + 4] = 1.0f - 2.0f * (xx * xx + zz * zz);
      R[j * 9 + 5] = 2.0f * (yy * zz - w * xx);
      R[j * 9 + 6] = 2.0f * (xx * zz - w * yy);
      R[j * 9 + 7] = 2.0f * (yy * zz + w * xx);
      R[j * 9 + 8] = 1.0f - 2.0f * (xx * xx + yy * yy);
    }
    P[0] = qf[0]; P[1] = qf[1]; P[2] = qf[2];

    // OFFSETS = np.linspace(0.2,0.6,18) f64 -> astype(f32); y[17]=0.6
    const double step = (0.6 - 0.2) / 17.0;
    for (int j = 1; j < 19; ++j) {
      int p = c_parents[j];
      double ov = (double)(j - 1) * step + 0.2;
      if (j == 18) ov = 0.6;
      float offy = (float)ov;
      // 'bij,j->bi' over offs=(0,offy,0): zero products exact either order
      float t0 = R[p * 9 + 1] * offy;
      float t1 = R[p * 9 + 4] * offy;
      float t2 = R[p * 9 + 7] * offy;
      P[j * 3 + 0] = P[p * 3 + 0] + t0;
      P[j * 3 + 1] = P[p * 3 + 1] + t1;
      P[j * 3 + 2] = P[p * 3 + 2] + t2;
      // rotg[j] = rotg[p] @ R[j]: c_einsum scalar, (p0+p1)+p2
      float m[9];
#pragma unroll
      for (int i = 0; i < 3; ++i)
#pragma unroll
        for (int c = 0; c < 3; ++c) {
          float p0 = R[p * 9 + i * 3 + 0] * R[j * 9 + 0 + c];
          float p1 = R[p * 9 + i * 3 + 1] * R[j * 9 + 3 + c];
          float p2 = R[p * 9 + i * 3 + 2] * R[j * 9 + 6 + c];
          m[i * 3 + c] = (p0 + p1) + p2;
        }
#pragma unroll
      for (int e = 0; e < 9; ++e) R[j * 9 + e] = m[e];
    }

    // output 1: P / (1.0f + 1e-9f) == P exactly in f32
    float* outPos = out + BATCH * 34 + sample * 57;
    for (int j = 0; j < 19; ++j) {
      outPos[j * 3 + 0] = P[j * 3 + 0];
      outPos[j * 3 + 1] = P[j * 3 + 1];
      outPos[j * 3 + 2] = P[j * 3 + 2];
    }

    // output 0: pose2d joints 0..8,11..18: x/(z+eps), (y-100)/(z+eps)
    float* out2d = out + sample * 34;
    int jj = 0;
    for (int j = 0; j < 19; ++j) {
      if (j == 9 || j == 10) continue;
      float zd = P[j * 3 + 2] + 1e-9f;
      float ym = P[j * 3 + 1] - 100.0f;
      out2d[jj * 2 + 0] = P[j * 3 + 0] / zd;
      out2d[jj * 2 + 1] = ym / zd;
      ++jj;
    }
  }
}

// ---------------------------------------------------------------------------
extern "C" void kernel_launch(void* const* d_in, const int* in_sizes, int n_in,
                              void* d_out, int out_size, void* d_ws, size_t ws_size,
                              hipStream_t stream) {
  const float* x   = (const float*)d_in[0];
  const float* w1  = (const float*)d_in[1];
  const float* b1  = (const float*)d_in[2];
  const float* w2  = (const float*)d_in[3];
  const float* b2  = (const float*)d_in[4];
  const float* w3  = (const float*)d_in[5];
  const float* b3  = (const float*)d_in[6];
  const float* fw1 = (const float*)d_in[7];
  const float* fb1 = (const float*)d_in[8];
  const float* fw2 = (const float*)d_in[9];
  const float* fb2 = (const float*)d_in[10];
  const float* fw3 = (const float*)d_in[11];
  const float* fb3 = (const float*)d_in[12];
  float* out = (float*)d_out;

  // pack weights for coalesced / pk-pair access (bit-exact: pure relocation)
  hipLaunchKernelGGL(k_pack, dim3((PACK_TOTAL + 255) / 256), dim3(256), 0, stream,
                     w2, w3, fw1, fw2, fw3);

  // conv stack: 1 sample per block
  hipLaunchKernelGGL(k_conv, dim3(BATCH), dim3(256), 0, stream,
                     x, w1, b1, b2, b3);

  // fc stack + tail: SPB samples per block
  hipLaunchKernelGGL(k_fc, dim3(BATCH / SPB), dim3(256), 0, stream,
                     fb1, fb2, fb3, out);
}